// Round 1
// 120.499 us; speedup vs baseline: 1.0833x; 1.0833x over previous
//
#include <hip/hip_runtime.h>
#include <hip/hip_bf16.h>

#define NPTS   131072
#define NNODES 2048
#define KSEL   32

// ---- knn decomposition ----
#define TKNN   256                 // threads per knn block
#define PPT    4                   // points per thread = 2 packed f32x2 chains
#define PPG_K  (TKNN * PPT)        // 1024 points per knn group
#define NGRP_K (NPTS / PPG_K)      // 128 knn groups
#define NCHUNK 8                   // node chunks (block-uniform -> s_load); halved atomics
#define CHN    (NNODES / NCHUNK)   // 256 nodes per chunk

// ---- grouping/scatter decomposition ----
#define GSZ    512                 // points per stability group
#define NG     (NPTS / GSZ)        // 256 groups

typedef unsigned int uint;
typedef unsigned short u16;
typedef unsigned long long u64;
typedef float f2 __attribute__((ext_vector_type(2)));

__device__ __forceinline__ f2 splat(float s) { return (f2){s, s}; }

// order-preserving fp32 -> u32 (handles tiny-negative cancellation results)
__device__ __forceinline__ uint f2ord(float d) {
    uint b = __float_as_uint(d);
    return (b & 0x80000000u) ? ~b : (b | 0x80000000u);
}
__device__ __forceinline__ float ord2f(uint t) {
    uint b = (t & 0x80000000u) ? (t ^ 0x80000000u) : ~t;
    return __uint_as_float(b);
}

// --- K0: pack nodes {x,y,z,|n|^2}; knnres init moved to hipMemsetAsync(0xFF) ---
__global__ __launch_bounds__(256) void prep_nodes(const float* __restrict__ nodes,
                                                  float4* __restrict__ n4) {
    int i = blockIdx.x * 256 + threadIdx.x;            // 8 blocks x 256 = 2048
    float x = nodes[3 * i], y = nodes[3 * i + 1], z = nodes[3 * i + 2];
    // |n|^2 with numpy's mul-then-add rounding
    float nn = __fadd_rn(__fadd_rn(__fmul_rn(x, x), __fmul_rn(y, y)), __fmul_rn(z, z));
    n4[i] = make_float4(x, y, z, nn);
}

// --- K1: partial 1-NN, 4 pts/thread as 2 packed-f32 chains (v_pk_* VOP3P) ---
// Distance per half: m = nx*x; t = fma(ny,y,m); r = fma(nz,z,t); d = (pp + r) + nn
// == reference (pp - 2*dot) + nn bit-exactly (unchanged from previous version).
// NEW: quad-deferred argmin. Per 4 nodes keep only
//   best' = min3(min3(best,d0,d1), d2, d3)      (v_min3_f32 x2, exact IEEE min)
// and record the quad base jj on STRICT improvement (first-occurrence preserved:
// later exact ties leave best unchanged -> strict < fails -> earlier quad kept).
// Endgame recomputes the 4 winning-quad distances with the identical op sequence
// (pk ops are lane-wise IEEE f32 -> scalar recompute is bit-identical) and picks
// the first exact match, restoring the precise node index.
__global__ __launch_bounds__(256) void knn_part(const float* __restrict__ pts,
                                                const float4* __restrict__ n4,
                                                u64* __restrict__ knnres) {
    int bid = blockIdx.x;
    int c   = bid & (NCHUNK - 1);            // block-uniform chunk
    int g   = bid >> 3;                      // knn point group
    int t   = threadIdx.x;

    // load 4 points, pack into 2 chains: chain q holds points (2q, 2q+1)
    f2 pp2[2], nx2[2], ny2[2], nz2[2];
    #pragma unroll
    for (int q = 0; q < 2; ++q) {
        #pragma unroll
        for (int h = 0; h < 2; ++h) {
            int pid = g * PPG_K + (2 * q + h) * TKNN + t;
            float p0 = pts[3 * pid], p1 = pts[3 * pid + 1], p2 = pts[3 * pid + 2];
            float pp = __fadd_rn(__fadd_rn(__fmul_rn(p0, p0), __fmul_rn(p1, p1)),
                                 __fmul_rn(p2, p2));
            pp2[q][h] = pp;
            nx2[q][h] = __fmul_rn(-2.0f, p0);   // exact
            ny2[q][h] = __fmul_rn(-2.0f, p1);
            nz2[q][h] = __fmul_rn(-2.0f, p2);
        }
    }

    const float4* np = n4 + c * CHN;         // block-uniform base -> scalar s_load
    float best[PPT];
    int   qb[PPT];
    #pragma unroll
    for (int p = 0; p < PPT; ++p) { best[p] = 3.4e38f; qb[p] = 0; }

    #pragma unroll 2
    for (int jj = 0; jj < CHN; jj += 4) {
        float4 v0 = np[jj + 0];              // uniform addr -> s_load_dwordx16 batches
        float4 v1 = np[jj + 1];
        float4 v2 = np[jj + 2];
        float4 v3 = np[jj + 3];

        f2 d[2][4];
        #pragma unroll
        for (int q = 0; q < 2; ++q) {
            {   f2 m = nx2[q] * splat(v0.x);
                f2 r = __builtin_elementwise_fma(ny2[q], splat(v0.y), m);
                r    = __builtin_elementwise_fma(nz2[q], splat(v0.z), r);
                d[q][0] = (pp2[q] + r) + splat(v0.w); }
            {   f2 m = nx2[q] * splat(v1.x);
                f2 r = __builtin_elementwise_fma(ny2[q], splat(v1.y), m);
                r    = __builtin_elementwise_fma(nz2[q], splat(v1.z), r);
                d[q][1] = (pp2[q] + r) + splat(v1.w); }
            {   f2 m = nx2[q] * splat(v2.x);
                f2 r = __builtin_elementwise_fma(ny2[q], splat(v2.y), m);
                r    = __builtin_elementwise_fma(nz2[q], splat(v2.z), r);
                d[q][2] = (pp2[q] + r) + splat(v2.w); }
            {   f2 m = nx2[q] * splat(v3.x);
                f2 r = __builtin_elementwise_fma(ny2[q], splat(v3.y), m);
                r    = __builtin_elementwise_fma(nz2[q], splat(v3.z), r);
                d[q][3] = (pp2[q] + r) + splat(v3.w); }
        }

        #pragma unroll
        for (int p = 0; p < PPT; ++p) {
            int q = p >> 1;
            float e0 = (p & 1) ? d[q][0].y : d[q][0].x;
            float e1 = (p & 1) ? d[q][1].y : d[q][1].x;
            float e2 = (p & 1) ? d[q][2].y : d[q][2].x;
            float e3 = (p & 1) ? d[q][3].y : d[q][3].x;
            float m1 = fminf(fminf(best[p], e0), e1);   // v_min3_f32
            float nb = fminf(fminf(m1, e2), e3);        // v_min3_f32
            qb[p]   = (nb < best[p]) ? jj : qb[p];      // strict: first quad wins
            best[p] = nb;                               // nb <= best always, exact
        }
    }

    // endgame: recover exact node index within the winning quad, then merge
    #pragma unroll
    for (int p = 0; p < PPT; ++p) {
        int q = p >> 1, h = p & 1;
        float nx = nx2[q][h], ny = ny2[q][h], nz = nz2[q][h], pp = pp2[q][h];
        float b  = best[p];
        int base = qb[p];
        float dd[4];
        #pragma unroll
        for (int o = 0; o < 4; ++o) {
            float4 v = np[base + o];         // per-lane addr, L2-hot (32 KB table)
            float m = __fmul_rn(nx, v.x);
            float r = __builtin_fmaf(ny, v.y, m);
            r       = __builtin_fmaf(nz, v.z, r);
            dd[o]   = __fadd_rn(__fadd_rn(pp, r), v.w);   // bit-identical to pk path
        }
        int off = 3;                          // descending chain -> first match wins
        if (dd[2] == b) off = 2;
        if (dd[1] == b) off = 1;
        if (dd[0] == b) off = 0;

        int pid = g * PPG_K + p * TKNN + t;
        u64 key = ((u64)f2ord(b) << 32) | (uint)(c * CHN + base + off);
        atomicMin(&knnres[pid], key);        // min key == (min d2, then min node idx)
    }
}

// --- K2: decode winners, write d2/id/pcd, per-group u16 histogram, zero patch ---
__global__ __launch_bounds__(256) void merge_hist(const u64* __restrict__ knnres,
                                                  float* __restrict__ out_d2,
                                                  float* __restrict__ out_id,
                                                  int* __restrict__ pcd,
                                                  u16* __restrict__ hist16,
                                                  float* __restrict__ patch) {
    __shared__ uint lh[NNODES];
    int g = blockIdx.x, t = threadIdx.x;
    patch[(size_t)g * 256 + t] = 0.0f;       // 256x256 = full 65536-float patch zeroed
    for (int i = t; i < NNODES; i += 256) lh[i] = 0;
    __syncthreads();

    #pragma unroll
    for (int q = 0; q < GSZ / 256; ++q) {
        int pid = g * GSZ + q * 256 + t;
        u64 key = knnres[pid];
        uint bi = (uint)key;                 // low 32: node index
        float d = ord2f((uint)(key >> 32));  // exact d2 decode
        atomicAdd(&lh[bi], 1u);
        out_d2[pid] = d;
        out_id[pid] = (float)bi;             // exact: bi < 2^24
        pcd[pid]    = (int)bi;
    }
    __syncthreads();
    for (int i = t; i < NNODES; i += 256)
        hist16[(size_t)g * NNODES + i] = (u16)lh[i];   // contiguous stores
}

// --- K3: per-node exclusive prefix across the 256 groups; offs in [node][group] ---
__global__ __launch_bounds__(256) void scan_offs(const u16* __restrict__ hist16,
                                                 uint* __restrict__ offs) {
    int t = threadIdx.x, lane = t & 63, wv = t >> 6;
    int node = blockIdx.x * 4 + wv;

    uint v0 = hist16[(size_t)(4 * lane + 0) * NNODES + node];
    uint v1 = hist16[(size_t)(4 * lane + 1) * NNODES + node];
    uint v2 = hist16[(size_t)(4 * lane + 2) * NNODES + node];
    uint v3 = hist16[(size_t)(4 * lane + 3) * NNODES + node];
    uint s = v0 + v1 + v2 + v3;
    uint a = s;
    #pragma unroll
    for (int d = 1; d < 64; d <<= 1) {
        uint y = __shfl_up(a, d, 64);
        if (lane >= d) a += y;
    }
    uint base = a - s;                        // exclusive across lanes
    uint4 o = make_uint4(base, base + v0, base + v0 + v1, base + v0 + v1 + v2);
    *(uint4*)(offs + (size_t)node * NG + 4 * lane) = o;   // contiguous 16B store
}

// --- K4: stable scatter of first-32 point indices per node ---
__global__ __launch_bounds__(256) void scatter_patch(const int* __restrict__ pcd,
                                                     const uint* __restrict__ offs,
                                                     float* __restrict__ patch) {
    __shared__ int ids[GSZ];
    int g = blockIdx.x, t = threadIdx.x;
    ids[t]       = pcd[g * GSZ + t];
    ids[256 + t] = pcd[g * GSZ + 256 + t];
    __syncthreads();

    int i0 = t, i1 = 256 + t;
    int my0 = ids[i0], my1 = ids[i1];
    int r0 = 0, r1 = 0;
    #pragma unroll 8
    for (int j = 0; j < GSZ; ++j) {
        int id = ids[j];                      // broadcast LDS read, conflict-free
        r0 += (j < i0 && id == my0) ? 1 : 0;
        r1 += (j < i1 && id == my1) ? 1 : 0;
    }
    uint rk0 = offs[(size_t)my0 * NG + g] + (uint)r0;
    uint rk1 = offs[(size_t)my1 * NG + g] + (uint)r1;
    if (rk0 < KSEL) patch[(size_t)my0 * KSEL + rk0] = (float)(g * GSZ + i0);
    if (rk1 < KSEL) patch[(size_t)my1 * KSEL + rk1] = (float)(g * GSZ + i1);
}

extern "C" void kernel_launch(void* const* d_in, const int* in_sizes, int n_in,
                              void* d_out, int out_size, void* d_ws, size_t ws_size,
                              hipStream_t stream) {
    const float* pts   = (const float*)d_in[0];
    const float* nodes = (const float*)d_in[1];

    float* out       = (float*)d_out;
    float* out_d2    = out;                  // 131072 floats
    float* out_id    = out + NPTS;           // 131072 floats
    float* out_patch = out + 2 * NPTS;       // 65536 floats

    // workspace: 4.6 MB
    char* ws = (char*)d_ws;
    u64*   knnres = (u64*) ws;                               // 1 MB   (131072 x u64)
    u16*   hist16 = (u16*) (ws + (1 << 20));                 // 1 MB   (256 x 2048 u16)
    uint*  offs   = (uint*) (ws + (2 << 20));                // 2 MB   (2048 x 256 u32)
    int*   pcd    = (int*)  (ws + (4 << 20));                // 512 KB
    float4* n4    = (float4*)(ws + (4 << 20) + (512 << 10)); // 32 KB

    hipMemsetAsync(knnres, 0xFF, (size_t)NPTS * sizeof(u64), stream);  // ~0ull keys
    prep_nodes<<<NNODES / 256, 256, 0, stream>>>(nodes, n4);
    knn_part<<<NGRP_K * NCHUNK, TKNN, 0, stream>>>(pts, n4, knnres);
    merge_hist<<<NG, 256, 0, stream>>>(knnres, out_d2, out_id, pcd, hist16, out_patch);
    scan_offs<<<NNODES / 4, 256, 0, stream>>>(hist16, offs);
    scatter_patch<<<NG, 256, 0, stream>>>(pcd, offs, out_patch);
}